// Round 8
// baseline (612.923 us; speedup 1.0000x reference)
//
#include <hip/hip_runtime.h>

// DigiCaps dynamic routing — m97-style LDS-staged MFMA pipeline.
// inputs [512,1152,8] f32, W [10,1152,16,8] f32, out v [512,10,16] f32.
// u_hat[b,j,i,d] = sum_k x[b,i,k] W[j,i,d,k]; logits b_t = u_hat . vsum
// (vsum = running sum of v's) -> u_hat never materialized.
//
// R4-R7 forensics: global->register frag loads are re-serialized by the
// register allocator (VGPR pinned 80-136 by occupancy heuristic) -> ~5900
// cy/i latency-bound, immune to batching/sched_barrier/launch_bounds.
// R8: global_load_lds (async, zero VGPR) stages W+x tiles into LDS,
// ds_read_b128 feeds MFMA (compiler emits fine-grained lgkmcnt - proven
// m97 structure). Block = 64 b (4 waves x 16) x 16 i, W-tile shared by all
// waves (4x reuse), two 8-i stages double-buffered. Waves own disjoint b
// -> no in-block reduction; epilogue = global fp32 atomics into s[512,10,16].
// mfma_f32_16x16x32_bf16, C-layout: lane&15 = b(col), (lane>>4)*4+reg = d.
// A: lanes kg==0 carry W k=0..7 (m=d=lane&15), kg>0 read a zeroed LDS pad
// -> exact K=8 contraction (verified R4/R6, absmax 3.9e-3).

#define NB 512
#define NI 1152
#define NJ 10
#define ND 16

typedef short  bf16x8 __attribute__((ext_vector_type(8)));
typedef float  f32x4  __attribute__((ext_vector_type(4)));

constexpr int   NBG  = 8;    // b-groups of 64
constexpr int   NIGB = 72;   // i-groups of 16
constexpr float EPS_ = 1e-7f;

constexpr size_t XB_ELEMS = (size_t)NB * NI * 8;       // bf16
constexpr size_t WB_ELEMS = (size_t)NJ * NI * ND * 8;  // bf16
constexpr int    XQ = 1179648;                         // x float4 quads
constexpr int    WQ = 368640;                          // W float4 quads

__device__ inline unsigned short f2bf(float f) {  // RNE f32 -> bf16
    unsigned u = __float_as_uint(f);
    return (unsigned short)((u + 0x7fffu + ((u >> 16) & 1u)) >> 16);
}

__global__ __launch_bounds__(256)
void conv_bf16(const float* __restrict__ x, const float* __restrict__ Wg,
               unsigned short* __restrict__ xb, unsigned short* __restrict__ wb)
{
    int t = blockIdx.x * 256 + threadIdx.x;
    if (t < XQ) {
        float4 v = ((const float4*)x)[t];
        ushort4 o;
        o.x = f2bf(v.x); o.y = f2bf(v.y); o.z = f2bf(v.z); o.w = f2bf(v.w);
        ((ushort4*)xb)[t] = o;
    } else if (t - XQ < WQ) {
        int u = t - XQ;
        float4 v = ((const float4*)Wg)[u];
        ushort4 o;
        o.x = f2bf(v.x); o.y = f2bf(v.y); o.z = f2bf(v.z); o.w = f2bf(v.w);
        ((ushort4*)wb)[u] = o;
    }
}

// async 16B global->LDS: per-lane global src, LDS dst = wave-uniform base + lane*16
__device__ inline void gl_lds16(const unsigned short* g, unsigned short* l) {
    __builtin_amdgcn_global_load_lds(
        (const __attribute__((address_space(1))) unsigned short*)g,
        (__attribute__((address_space(3))) unsigned short*)l, 16, 0, 0);
}

template <int MODE>
__global__ __launch_bounds__(256, 2)
void caps_pass(const unsigned short* __restrict__ xb,
               const unsigned short* __restrict__ wb,
               const float* __restrict__ vsum_g,
               float* __restrict__ s_g)
{
    // granule = 16 B (8 bf16). wlds: [t<8][j][d] ; xlds: [t<8][b^]
    __shared__ unsigned short wlds[2][10240];   // 2 x 20480 B
    __shared__ unsigned short xlds[2][4096];    // 2 x 8192 B
    __shared__ unsigned short zpad[8];          // 16 B of zeros (A k>=8 rows)

    const int tid = threadIdx.x, lane = tid & 63, w = tid >> 6;
    const int bl = lane & 15, kg = lane >> 4;
    const int bg = blockIdx.x, ig = blockIdx.y;
    const int i0 = ig * 16, b0 = bg * 64;
    const int b  = b0 + w * 16 + bl;

    if (tid < 8) zpad[tid] = 0;

    // stage 8 i's (ii0..ii0+7) of W (1280 granules) + x (512 granules) into buf
    auto stage = [&](int buf, int ii0) {
#pragma unroll
        for (int r = 0; r < 5; ++r) {                    // W: wave w -> n = w*320+r*64+lane
            int n   = w * 320 + r * 64;
            int idx = n + lane;
            int il  = idx / 160, rem = idx - il * 160;   // rem = j*16 + d
            const unsigned short* src =
                wb + ((size_t)(rem >> 4) * NI + (ii0 + il)) * 128 + (rem & 15) * 8;
            gl_lds16(src, &wlds[buf][n * 8]);
        }
#pragma unroll
        for (int r = 0; r < 2; ++r) {                    // x: n = (w*2+r)*64+lane
            int n   = (w * 2 + r) * 64;
            int idx = n + lane;
            int il  = idx >> 6, bh = idx & 63;
            const unsigned short* src = xb + ((size_t)(b0 + bh) * NI + (ii0 + il)) * 8;
            gl_lds16(src, &xlds[buf][n * 8]);
        }
    };

    f32x4 vs[NJ];
    if (MODE == 1) {
#pragma unroll
        for (int j = 0; j < NJ; ++j)
            vs[j] = *(const f32x4*)(vsum_g + (size_t)b * 160 + j * 16 + kg * 4);
    }

    stage(0, i0);
    __syncthreads();          // drains stage(0) vmcnt + zpad
    stage(1, i0 + 8);

    const f32x4 zero = {0.f, 0.f, 0.f, 0.f};
    f32x4 sacc[NJ];
#pragma unroll
    for (int j = 0; j < NJ; ++j) sacc[j] = zero;

#pragma unroll
    for (int half = 0; half < 2; ++half) {
#pragma unroll
        for (int t = 0; t < 8; ++t) {
            bf16x8 xf = *(const bf16x8*)&xlds[half][(t * 64 + w * 16 + bl) * 8];

            f32x4 uh[NJ];
#pragma unroll
            for (int j = 0; j < NJ; ++j) {
                const unsigned short* ap = (kg == 0)
                    ? &wlds[half][((t * 10 + j) * 16 + bl) * 8] : &zpad[0];
                bf16x8 af = *(const bf16x8*)ap;
                if (MODE == 0)
                    sacc[j] = __builtin_amdgcn_mfma_f32_16x16x32_bf16(af, xf, sacc[j], 0, 0, 0);
                else
                    uh[j] = __builtin_amdgcn_mfma_f32_16x16x32_bf16(af, xf, zero, 0, 0, 0);
            }

            if (MODE == 1) {
                float bd[NJ];
#pragma unroll
                for (int j = 0; j < NJ; ++j) {
                    float v = uh[j][0] * vs[j][0] + uh[j][1] * vs[j][1]
                            + uh[j][2] * vs[j][2] + uh[j][3] * vs[j][3];
                    v += __shfl_xor(v, 16, 64);   // reduce the 4 d-quads
                    v += __shfl_xor(v, 32, 64);
                    bd[j] = v;
                }
                float m = bd[0];
#pragma unroll
                for (int j = 1; j < NJ; ++j) m = fmaxf(m, bd[j]);
                float Z = 0.f;
#pragma unroll
                for (int j = 0; j < NJ; ++j) { bd[j] = __expf(bd[j] - m); Z += bd[j]; }
                const float rZ = 1.f / Z;
#pragma unroll
                for (int j = 0; j < NJ; ++j) {
                    const float c = bd[j] * rZ;
                    sacc[j] += c * uh[j];
                }
            }
        }
        if (half == 0) __syncthreads();   // stage(1) landed
    }

    // epilogue: waves own disjoint b -> straight global fp32 atomics
    float* pb = s_g + (size_t)b * 160 + kg * 4;
#pragma unroll
    for (int j = 0; j < NJ; ++j)
#pragma unroll
        for (int r = 0; r < 4; ++r)
            atomicAdd(pb + j * 16 + r, sacc[j][r]);
}

// s_g[b,j,d] -> squash over d (16-lane shfl) -> vsum/out; re-zero s_g for next pass.
__global__ __launch_bounds__(256)
void squash_reduce(float* __restrict__ s_g, float* __restrict__ vsum_g,
                   float* __restrict__ out, float alpha, int mode)
{
    const int t = blockIdx.x * 256 + threadIdx.x;   // < 81920 = b*160 + j*16 + d
    const float s = s_g[t] * alpha;

    float sq = s * s;
    sq += __shfl_xor(sq, 1, 64);
    sq += __shfl_xor(sq, 2, 64);
    sq += __shfl_xor(sq, 4, 64);
    sq += __shfl_xor(sq, 8, 64);
    const float sc = sq / ((1.f + sq) * sqrtf(sq + EPS_));
    const float v  = sc * s;

    if (mode == 0)      vsum_g[t] = v;
    else if (mode == 1) vsum_g[t] += v;
    else                out[t] = v;
    if (mode < 2)       s_g[t] = 0.f;   // ready for next pass's atomics
}

extern "C" void kernel_launch(void* const* d_in, const int* in_sizes, int n_in,
                              void* d_out, int out_size, void* d_ws, size_t ws_size,
                              hipStream_t stream)
{
    const float* inp = (const float*)d_in[0];
    const float* Wg  = (const float*)d_in[1];
    float* out = (float*)d_out;

    unsigned short* xbp = (unsigned short*)d_ws;
    unsigned short* wbp = xbp + XB_ELEMS;
    float* s_g  = (float*)((char*)d_ws + (XB_ELEMS + WB_ELEMS) * 2);  // [512][10][16]
    float* vsum = s_g + (size_t)NB * NJ * ND;

    hipMemsetAsync(s_g, 0, (size_t)NB * NJ * ND * sizeof(float), stream);
    conv_bf16<<<(XQ + WQ + 255) / 256, 256, 0, stream>>>(inp, Wg, xbp, wbp);

    dim3 grid(NBG, NIGB);   // (8,72) = 576 blocks
    // iter 0: c uniform 1/10 (folded into alpha)
    caps_pass<0><<<grid, 256, 0, stream>>>(xbp, wbp, nullptr, s_g);
    squash_reduce<<<320, 256, 0, stream>>>(s_g, vsum, out, 0.1f, 0);
    // iter 1: logits = u_hat . v0
    caps_pass<1><<<grid, 256, 0, stream>>>(xbp, wbp, vsum, s_g);
    squash_reduce<<<320, 256, 0, stream>>>(s_g, vsum, out, 1.0f, 1);
    // iter 2: logits = u_hat . (v0+v1)
    caps_pass<1><<<grid, 256, 0, stream>>>(xbp, wbp, vsum, s_g);
    squash_reduce<<<320, 256, 0, stream>>>(s_g, vsum, out, 1.0f, 2);
}

// Round 9
// 535.107 us; speedup vs baseline: 1.1454x; 1.1454x over previous
//
#include <hip/hip_runtime.h>

// DigiCaps dynamic routing — LDS-staged MFMA pipeline, atomic-free epilogue.
// inputs [512,1152,8] f32, W [10,1152,16,8] f32, out v [512,10,16] f32.
// u_hat[b,j,i,d] = sum_k x[b,i,k] W[j,i,d,k]; logits b_t = u_hat . vsum
// (vsum = running sum of v's) -> u_hat never materialized.
//
// R8 forensics: compute core was fine (VALU 12us, MFMA 2.3us busy-time) but
// the epilogue's 5.9M global fp32 atomicAdds became ~64B memory-side RMWs
// (WRITE_SIZE 397 MB = 5.9M x 64B) -> 298us atomic storm. R9: waves own
// disjoint b, so partials go to a block-private slice part[ig][b][160]
// (coalesced float4, full lines, 23.6 MB/pass); squash_reduce sums 72
// ig-partials. x staging: xlds dropped; 16 loop-invariant per-lane register
// loads (B-frag only needs kg==0 lanes valid). W stays on the proven
// global_load_lds double-buffer; ds_read_b128 feeds MFMA.
// mfma_f32_16x16x32_bf16, C-layout: lane&15 = b(col), (lane>>4)*4+reg = d.
// A: kg==0 lanes carry W k=0..7 (m=d), kg>0 read a zeroed LDS granule ->
// exact K=8 contraction (verified R4-R8, absmax 3.9e-3).

#define NB 512
#define NI 1152
#define NJ 10
#define ND 16

typedef short  bf16x8 __attribute__((ext_vector_type(8)));
typedef float  f32x4  __attribute__((ext_vector_type(4)));

constexpr int   NBG  = 8;    // b-groups of 64
constexpr int   NIGB = 72;   // i-groups of 16
constexpr float EPS_ = 1e-7f;

constexpr size_t XB_ELEMS = (size_t)NB * NI * 8;       // bf16
constexpr size_t WB_ELEMS = (size_t)NJ * NI * ND * 8;  // bf16
constexpr int    XQ = 1179648;                         // x float4 quads
constexpr int    WQ = 368640;                          // W float4 quads

__device__ inline unsigned short f2bf(float f) {  // RNE f32 -> bf16
    unsigned u = __float_as_uint(f);
    return (unsigned short)((u + 0x7fffu + ((u >> 16) & 1u)) >> 16);
}

__global__ __launch_bounds__(256)
void conv_bf16(const float* __restrict__ x, const float* __restrict__ Wg,
               unsigned short* __restrict__ xb, unsigned short* __restrict__ wb)
{
    int t = blockIdx.x * 256 + threadIdx.x;
    if (t < XQ) {
        float4 v = ((const float4*)x)[t];
        ushort4 o;
        o.x = f2bf(v.x); o.y = f2bf(v.y); o.z = f2bf(v.z); o.w = f2bf(v.w);
        ((ushort4*)xb)[t] = o;
    } else if (t - XQ < WQ) {
        int u = t - XQ;
        float4 v = ((const float4*)Wg)[u];
        ushort4 o;
        o.x = f2bf(v.x); o.y = f2bf(v.y); o.z = f2bf(v.z); o.w = f2bf(v.w);
        ((ushort4*)wb)[u] = o;
    }
}

// async 16B global->LDS: per-lane global src, LDS dst = wave-uniform base + lane*16
__device__ inline void gl_lds16(const unsigned short* g, unsigned short* l) {
    __builtin_amdgcn_global_load_lds(
        (const __attribute__((address_space(1))) unsigned short*)g,
        (__attribute__((address_space(3))) unsigned short*)l, 16, 0, 0);
}

template <int MODE>
__global__ __launch_bounds__(256, 2)
void caps_pass(const unsigned short* __restrict__ xb,
               const unsigned short* __restrict__ wb,
               const float* __restrict__ vsum_g,
               float* __restrict__ part)
{
    // wlds granule layout per stage of 8 i: [il][j][d], 1280 granules x 16B.
    __shared__ unsigned short wlds[2][10240];
    __shared__ unsigned short zpad[8];

    const int tid = threadIdx.x, lane = tid & 63, w = tid >> 6;
    const int bl = lane & 15, kg = lane >> 4;
    const int bg = blockIdx.x, ig = blockIdx.y;
    const int i0 = ig * 16, b0 = bg * 64;
    const int b  = b0 + w * 16 + bl;

    if (tid < 8) zpad[tid] = 0;

    // stage 8 i's of W (1280 granules) into buf; coalesced 1KB per instr
    auto stage = [&](int buf, int ii0) {
#pragma unroll
        for (int r = 0; r < 5; ++r) {
            int n   = w * 320 + r * 64;
            int idx = n + lane;
            int il  = idx / 160, rem = idx - il * 160;   // rem = j*16 + d
            const unsigned short* src =
                wb + ((size_t)(rem >> 4) * NI + (ii0 + il)) * 128 + (rem & 15) * 8;
            gl_lds16(src, &wlds[buf][n * 8]);
        }
    };

    stage(0, i0);

    // loop-invariant register loads: x rows (B-frags) and vsum
    bf16x8 xreg[16];
#pragma unroll
    for (int t = 0; t < 16; ++t)
        xreg[t] = *(const bf16x8*)(xb + ((size_t)b * NI + i0 + t) * 8);

    f32x4 vs[NJ];
    if (MODE == 1) {
#pragma unroll
        for (int j = 0; j < NJ; ++j)
            vs[j] = *(const f32x4*)(vsum_g + (size_t)b * 160 + j * 16 + kg * 4);
    }

    __syncthreads();          // stage(0) + zpad landed
    stage(1, i0 + 8);

    const f32x4 zero = {0.f, 0.f, 0.f, 0.f};
    f32x4 sacc[NJ];
#pragma unroll
    for (int j = 0; j < NJ; ++j) sacc[j] = zero;

#pragma unroll
    for (int half = 0; half < 2; ++half) {
#pragma unroll
        for (int t = 0; t < 8; ++t) {
            const bf16x8 xf = xreg[half * 8 + t];

            f32x4 uh[NJ];
#pragma unroll
            for (int j = 0; j < NJ; ++j) {
                const unsigned short* ap = (kg == 0)
                    ? &wlds[half][((t * 10 + j) * 16 + bl) * 8] : &zpad[0];
                bf16x8 af = *(const bf16x8*)ap;
                if (MODE == 0)
                    sacc[j] = __builtin_amdgcn_mfma_f32_16x16x32_bf16(af, xf, sacc[j], 0, 0, 0);
                else
                    uh[j] = __builtin_amdgcn_mfma_f32_16x16x32_bf16(af, xf, zero, 0, 0, 0);
            }

            if (MODE == 1) {
                float bd[NJ];
#pragma unroll
                for (int j = 0; j < NJ; ++j) {
                    float v = uh[j][0] * vs[j][0] + uh[j][1] * vs[j][1]
                            + uh[j][2] * vs[j][2] + uh[j][3] * vs[j][3];
                    v += __shfl_xor(v, 16, 64);   // reduce the 4 d-quads
                    v += __shfl_xor(v, 32, 64);
                    bd[j] = v;
                }
                float m = bd[0];
#pragma unroll
                for (int j = 1; j < NJ; ++j) m = fmaxf(m, bd[j]);
                float Z = 0.f;
#pragma unroll
                for (int j = 0; j < NJ; ++j) { bd[j] = __expf(bd[j] - m); Z += bd[j]; }
                const float rZ = 1.f / Z;
#pragma unroll
                for (int j = 0; j < NJ; ++j) {
                    const float c = bd[j] * rZ;
                    sacc[j] += c * uh[j];
                }
            }
        }
        if (half == 0) __syncthreads();   // stage(1) landed
    }

    // epilogue: block-private partial slice, coalesced float4, full 64B lines
    float* pp = part + ((size_t)ig * NB + b) * 160 + kg * 4;
#pragma unroll
    for (int j = 0; j < NJ; ++j) {
        f32x4 v = sacc[j];
        *(float4*)(pp + j * 16) = make_float4(v[0], v[1], v[2], v[3]);
    }
}

// Sum 72 ig-partials (coalesced per slice), scale, squash over d (16-lane
// shfl), update vsum/out. t = b*160 + j*16 + d.
__global__ __launch_bounds__(256)
void squash_reduce(const float* __restrict__ part, float* __restrict__ vsum_g,
                   float* __restrict__ out, float alpha, int mode)
{
    const int t = blockIdx.x * 256 + threadIdx.x;   // < 81920
    const float* p = part + t;
    float a0 = 0.f, a1 = 0.f, a2 = 0.f, a3 = 0.f;
#pragma unroll
    for (int ig = 0; ig < NIGB; ig += 4) {
        a0 += p[(size_t)ig * 81920];
        a1 += p[(size_t)(ig + 1) * 81920];
        a2 += p[(size_t)(ig + 2) * 81920];
        a3 += p[(size_t)(ig + 3) * 81920];
    }
    const float s = ((a0 + a1) + (a2 + a3)) * alpha;

    float sq = s * s;
    sq += __shfl_xor(sq, 1, 64);
    sq += __shfl_xor(sq, 2, 64);
    sq += __shfl_xor(sq, 4, 64);
    sq += __shfl_xor(sq, 8, 64);
    const float sc = sq / ((1.f + sq) * sqrtf(sq + EPS_));
    const float v  = sc * s;

    if (mode == 0)      vsum_g[t] = v;
    else if (mode == 1) vsum_g[t] += v;
    else                out[t] = v;
}

extern "C" void kernel_launch(void* const* d_in, const int* in_sizes, int n_in,
                              void* d_out, int out_size, void* d_ws, size_t ws_size,
                              hipStream_t stream)
{
    const float* inp = (const float*)d_in[0];
    const float* Wg  = (const float*)d_in[1];
    float* out = (float*)d_out;

    unsigned short* xbp = (unsigned short*)d_ws;
    unsigned short* wbp = xbp + XB_ELEMS;
    float* part = (float*)((char*)d_ws + (XB_ELEMS + WB_ELEMS) * 2);  // [72][512][160]
    float* vsum = part + (size_t)NIGB * NB * 160;

    conv_bf16<<<(XQ + WQ + 255) / 256, 256, 0, stream>>>(inp, Wg, xbp, wbp);

    dim3 grid(NBG, NIGB);   // (8,72) = 576 blocks
    // iter 0: c uniform 1/10 (folded into alpha)
    caps_pass<0><<<grid, 256, 0, stream>>>(xbp, wbp, nullptr, part);
    squash_reduce<<<320, 256, 0, stream>>>(part, vsum, out, 0.1f, 0);
    // iter 1: logits = u_hat . v0
    caps_pass<1><<<grid, 256, 0, stream>>>(xbp, wbp, vsum, part);
    squash_reduce<<<320, 256, 0, stream>>>(part, vsum, out, 1.0f, 1);
    // iter 2: logits = u_hat . (v0+v1)
    caps_pass<1><<<grid, 256, 0, stream>>>(xbp, wbp, vsum, part);
    squash_reduce<<<320, 256, 0, stream>>>(part, vsum, out, 1.0f, 2);
}

// Round 10
// 472.001 us; speedup vs baseline: 1.2986x; 1.1337x over previous
//
#include <hip/hip_runtime.h>

// DigiCaps dynamic routing — LDS-staged MFMA pipeline, dense-line I/O.
// inputs [512,1152,8] f32, W [10,1152,16,8] f32, out v [512,10,16] f32.
// u_hat[b,j,i,d] = sum_k x[b,i,k] W[j,i,d,k]; logits b_t = u_hat . vsum
// (vsum = running sum of v's) -> u_hat never materialized.
//
// R8/R9 forensics: ~170MB FETCH + ~330MB WRITE per pass regardless of
// atomic-vs-store epilogue = partial-line amplification from 16B stores at
// 640B stride and 16B x-loads at 18KB stride (R3's contiguous LDS->global
// copy showed 1x traffic on the same problem). R10: (1) epilogue bounces
// sacc through LDS, then block-contiguous 512B/wave full-line writes;
// (2) x staged by global_load_lds with XOR-swizzled slots (global side
// coalesced 256B/row, LDS side conflict-free); (3) partials in bf16.
// mfma_f32_16x16x32_bf16, C-layout: lane&15 = b(col), (lane>>4)*4+reg = d.
// A: kg==0 lanes carry W k=0..7, kg>0 read a zeroed LDS granule -> exact
// K=8 contraction (verified R4-R9, absmax 3.9e-3).

#define NB 512
#define NI 1152
#define NJ 10
#define ND 16

typedef short  bf16x8 __attribute__((ext_vector_type(8)));
typedef float  f32x4  __attribute__((ext_vector_type(4)));

constexpr int   NBG  = 8;    // b-groups of 64
constexpr int   NIGB = 72;   // i-groups of 16
constexpr float EPS_ = 1e-7f;

constexpr size_t XB_ELEMS = (size_t)NB * NI * 8;       // bf16
constexpr size_t WB_ELEMS = (size_t)NJ * NI * ND * 8;  // bf16
constexpr int    XQ = 1179648;                         // x float4 quads
constexpr int    WQ = 368640;                          // W float4 quads

__device__ inline unsigned short f2bf(float f) {  // RNE f32 -> bf16
    unsigned u = __float_as_uint(f);
    return (unsigned short)((u + 0x7fffu + ((u >> 16) & 1u)) >> 16);
}

__global__ __launch_bounds__(256)
void conv_bf16(const float* __restrict__ x, const float* __restrict__ Wg,
               unsigned short* __restrict__ xb, unsigned short* __restrict__ wb)
{
    int t = blockIdx.x * 256 + threadIdx.x;
    if (t < XQ) {
        float4 v = ((const float4*)x)[t];
        ushort4 o;
        o.x = f2bf(v.x); o.y = f2bf(v.y); o.z = f2bf(v.z); o.w = f2bf(v.w);
        ((ushort4*)xb)[t] = o;
    } else if (t - XQ < WQ) {
        int u = t - XQ;
        float4 v = ((const float4*)Wg)[u];
        ushort4 o;
        o.x = f2bf(v.x); o.y = f2bf(v.y); o.z = f2bf(v.z); o.w = f2bf(v.w);
        ((ushort4*)wb)[u] = o;
    }
}

// async 16B global->LDS: per-lane global src; LDS dst = wave-uniform base,
// HW scatters at base + lane*16.
__device__ inline void gl_lds16(const unsigned short* g, unsigned short* l) {
    __builtin_amdgcn_global_load_lds(
        (const __attribute__((address_space(1))) unsigned short*)g,
        (__attribute__((address_space(3))) unsigned short*)l, 16, 0, 0);
}

template <int MODE>
__global__ __launch_bounds__(256, 2)
void caps_pass(const unsigned short* __restrict__ xb,
               const unsigned short* __restrict__ wb,
               const float* __restrict__ vsum_g,
               unsigned short* __restrict__ part)
{
    // smem map (bytes): [0,40960) wlds 2x1280 granules; [40960,57344) xlds
    // 1024 granules (swizzled); [57344,57360) zpad. Epilogue aliases
    // [0,41984) as float s_out[64][164] after the final barrier.
    __shared__ __align__(16) char smem[57360];
    unsigned short* wlds = (unsigned short*)smem;
    unsigned short* xlds = (unsigned short*)(smem + 40960);
    unsigned short* zpad = (unsigned short*)(smem + 57344);

    const int tid = threadIdx.x, lane = tid & 63, w = tid >> 6;
    const int bl = lane & 15, kg = lane >> 4;
    const int bg = blockIdx.x, ig = blockIdx.y;
    const int i0 = ig * 16, b0 = bg * 64;
    const int b  = b0 + w * 16 + bl;
    const int brow = w * 16 + bl;

    if (tid < 8) zpad[tid] = 0;

    // W stage: 8 i's -> 1280 granules [il][j][d]; global side 256B/j coalesced.
    auto stageW = [&](int buf, int ii0) {
#pragma unroll
        for (int r = 0; r < 5; ++r) {
            int n   = w * 320 + r * 64;
            int idx = n + lane;
            int il  = idx / 160, rem = idx - il * 160;   // rem = j*16 + d
            const unsigned short* src =
                wb + ((size_t)(rem >> 4) * NI + (ii0 + il)) * 128 + (rem & 15) * 8;
            gl_lds16(src, wlds + buf * 10240 + n * 8);
        }
    };

    // x stage (loop-invariant, once): slot = brow*16 + sg, holds granule
    // gr = sg ^ (brow&7) of row brow. Global side: 16 consecutive lanes read
    // one 256B row chunk (full lines); LDS read side lands conflict-free.
#pragma unroll
    for (int r = 0; r < 4; ++r) {
        int n    = w * 256 + r * 64;
        int idx  = n + lane;
        int br   = idx >> 4, sg = idx & 15;
        int gr   = sg ^ (br & 7);
        const unsigned short* src = xb + ((size_t)(b0 + br) * NI + i0 + gr) * 8;
        gl_lds16(src, xlds + n * 8);
    }
    stageW(0, i0);

    f32x4 vs[NJ];
    if (MODE == 1) {
#pragma unroll
        for (int j = 0; j < NJ; ++j)
            vs[j] = *(const f32x4*)(vsum_g + (size_t)b * 160 + j * 16 + kg * 4);
    }

    __syncthreads();            // x + W stage 0 + zpad landed
    stageW(1, i0 + 8);

    const f32x4 zero = {0.f, 0.f, 0.f, 0.f};
    f32x4 sacc[NJ];
#pragma unroll
    for (int j = 0; j < NJ; ++j) sacc[j] = zero;

#pragma unroll
    for (int half = 0; half < 2; ++half) {
#pragma unroll
        for (int t = 0; t < 8; ++t) {
            const int it = half * 8 + t;
            bf16x8 xf = *(const bf16x8*)(xlds + (brow * 16 + (it ^ (brow & 7))) * 8);

            f32x4 uh[NJ];
#pragma unroll
            for (int j = 0; j < NJ; ++j) {
                const unsigned short* ap = (kg == 0)
                    ? (wlds + half * 10240 + ((t * 10 + j) * 16 + bl) * 8) : zpad;
                bf16x8 af = *(const bf16x8*)ap;
                if (MODE == 0)
                    sacc[j] = __builtin_amdgcn_mfma_f32_16x16x32_bf16(af, xf, sacc[j], 0, 0, 0);
                else
                    uh[j] = __builtin_amdgcn_mfma_f32_16x16x32_bf16(af, xf, zero, 0, 0, 0);
            }

            if (MODE == 1) {
                float bd[NJ];
#pragma unroll
                for (int j = 0; j < NJ; ++j) {
                    float v = uh[j][0] * vs[j][0] + uh[j][1] * vs[j][1]
                            + uh[j][2] * vs[j][2] + uh[j][3] * vs[j][3];
                    v += __shfl_xor(v, 16, 64);   // reduce the 4 d-quads
                    v += __shfl_xor(v, 32, 64);
                    bd[j] = v;
                }
                float m = bd[0];
#pragma unroll
                for (int j = 1; j < NJ; ++j) m = fmaxf(m, bd[j]);
                float Z = 0.f;
#pragma unroll
                for (int j = 0; j < NJ; ++j) { bd[j] = __expf(bd[j] - m); Z += bd[j]; }
                const float rZ = 1.f / Z;
#pragma unroll
                for (int j = 0; j < NJ; ++j) {
                    const float c = bd[j] * rZ;
                    sacc[j] += c * uh[j];
                }
            }
        }
        if (half == 0) __syncthreads();   // stage 1 landed
    }

    // ---- epilogue: sacc -> LDS (padded stride 164) -> dense contiguous write
    __syncthreads();                      // all wlds/xlds reads complete
    float* s_out = (float*)smem;
#pragma unroll
    for (int j = 0; j < NJ; ++j)
        *(f32x4*)(s_out + brow * 164 + j * 16 + kg * 4) = sacc[j];
    __syncthreads();

    unsigned short* pp = part + ((size_t)ig * NB + b0) * 160;
#pragma unroll
    for (int r = 0; r < 10; ++r) {
        int idx = tid + r * 256;                 // 2560 float4 chunks = 64x160
        int br  = idx / 40, f4 = idx - br * 40;
        f32x4 v = *(const f32x4*)(s_out + br * 164 + f4 * 4);
        ushort4 o;
        o.x = f2bf(v[0]); o.y = f2bf(v[1]); o.z = f2bf(v[2]); o.w = f2bf(v[3]);
        *(ushort4*)(pp + idx * 4) = o;           // 512B contiguous per wave
    }
}

// Sum 72 bf16 ig-partials in fp32, scale, squash over d (16-lane shfl),
// update vsum/out. t = b*160 + j*16 + d.
__global__ __launch_bounds__(256)
void squash_reduce(const unsigned short* __restrict__ part,
                   float* __restrict__ vsum_g, float* __restrict__ out,
                   float alpha, int mode)
{
    const int t = blockIdx.x * 256 + threadIdx.x;   // < 81920
    const unsigned short* p = part + t;
    float a0 = 0.f, a1 = 0.f, a2 = 0.f, a3 = 0.f;
#pragma unroll
    for (int ig = 0; ig < NIGB; ig += 4) {
        a0 += __uint_as_float((unsigned)p[(size_t)ig * 81920] << 16);
        a1 += __uint_as_float((unsigned)p[(size_t)(ig + 1) * 81920] << 16);
        a2 += __uint_as_float((unsigned)p[(size_t)(ig + 2) * 81920] << 16);
        a3 += __uint_as_float((unsigned)p[(size_t)(ig + 3) * 81920] << 16);
    }
    const float s = ((a0 + a1) + (a2 + a3)) * alpha;

    float sq = s * s;
    sq += __shfl_xor(sq, 1, 64);
    sq += __shfl_xor(sq, 2, 64);
    sq += __shfl_xor(sq, 4, 64);
    sq += __shfl_xor(sq, 8, 64);
    const float sc = sq / ((1.f + sq) * sqrtf(sq + EPS_));
    const float v  = sc * s;

    if (mode == 0)      vsum_g[t] = v;
    else if (mode == 1) vsum_g[t] += v;
    else                out[t] = v;
}

extern "C" void kernel_launch(void* const* d_in, const int* in_sizes, int n_in,
                              void* d_out, int out_size, void* d_ws, size_t ws_size,
                              hipStream_t stream)
{
    const float* inp = (const float*)d_in[0];
    const float* Wg  = (const float*)d_in[1];
    float* out = (float*)d_out;

    unsigned short* xbp  = (unsigned short*)d_ws;
    unsigned short* wbp  = xbp + XB_ELEMS;
    unsigned short* part = wbp + WB_ELEMS;                    // [72][512][160] bf16
    float* vsum = (float*)(part + (size_t)NIGB * NB * 160);   // [512][10][16] f32

    conv_bf16<<<(XQ + WQ + 255) / 256, 256, 0, stream>>>(inp, Wg, xbp, wbp);

    dim3 grid(NBG, NIGB);   // (8,72) = 576 blocks
    // iter 0: c uniform 1/10 (folded into alpha)
    caps_pass<0><<<grid, 256, 0, stream>>>(xbp, wbp, nullptr, part);
    squash_reduce<<<320, 256, 0, stream>>>(part, vsum, out, 0.1f, 0);
    // iter 1: logits = u_hat . v0
    caps_pass<1><<<grid, 256, 0, stream>>>(xbp, wbp, vsum, part);
    squash_reduce<<<320, 256, 0, stream>>>(part, vsum, out, 1.0f, 1);
    // iter 2: logits = u_hat . (v0+v1)
    caps_pass<1><<<grid, 256, 0, stream>>>(xbp, wbp, vsum, part);
    squash_reduce<<<320, 256, 0, stream>>>(part, vsum, out, 1.0f, 2);
}

// Round 11
// 202.548 us; speedup vs baseline: 3.0261x; 2.3303x over previous
//
#include <hip/hip_runtime.h>

// DigiCaps dynamic routing — u_hat materialization + streaming routing passes.
// inputs [512,1152,8] f32, W [10,1152,16,8] f32, out v [512,10,16] f32.
//
// R8-R10 forensics: the recompute strategy is walled in both directions —
// global->reg frag chains are latency-serialized by the register allocator
// (R4-R7, ~73-94us/pass), and the global_load_lds staging structure drags a
// ~0.5GB/pass phantom FETCH+WRITE (R8-R10, ~210us/pass, present even in the
// 60-VGPR MODE-0 kernel => not spills/atomics/epilogue). R11 changes the
// algorithm: produce u_hat ONCE in bf16 (188MB) in consumer-native fragment
// layout u5[i][jp][b][kg][j01][d4], then each routing pass is a pure dense
// stream (16B/lane, 1KB/instr contiguous). Producer K-loop is fully LDS-fed
// (ordinary loads + ds_write staging; NO global_load_lds anywhere). Iter-0's
// uniform sum accumulates in producer registers -> only 2 streaming passes.
// MFMA f32_16x16x32_bf16, C-layout: lane&15=b(col), (lane>>4)*4+reg=d(row);
// A from W (kg==0 lanes real, kg>0 zeroed granule -> exact K=8). Verified
// R4-R10, absmax 3.9e-3.

#define NB 512
#define NI 1152
#define NJ 10
#define ND 16

typedef short          bf16x8 __attribute__((ext_vector_type(8)));
typedef unsigned short u16x8  __attribute__((ext_vector_type(8)));
typedef float          f32x4  __attribute__((ext_vector_type(4)));

constexpr float EPS_ = 1e-7f;

// ---- main-path sizes (shorts) ----
constexpr size_t U5_SH   = (size_t)NI * 5 * NB * 4 * 8;   // 94,371,840 (188.7 MB)
constexpr size_t PART_SH = (size_t)72 * NB * 160;         // 5,898,240  (11.8 MB)
constexpr size_t WS_MAIN = (U5_SH + PART_SH) * 2 + (size_t)NB * 160 * 4;  // ~201 MB

__device__ inline unsigned short f2bf(float f) {   // RNE f32->bf16
    unsigned u = __float_as_uint(f);
    return (unsigned short)((u + 0x7fffu + ((u >> 16) & 1u)) >> 16);
}
__device__ inline float bf2f(unsigned short u) {
    return __uint_as_float((unsigned)u << 16);
}

// ============================ MAIN PATH ============================

// Producer: block = 64 b (4 waves x 16) x 16 i. W-tile (40KB bf16) + x-tile
// (16KB, XOR-swizzled) staged via ordinary loads + ds_write (cvt inline from
// f32). K-loop: ds_read -> MFMA -> pack -> dense u5 stores; accumulates the
// iter-0 uniform sum in registers; epilogue = LDS-bounce bf16 partials.
__global__ __launch_bounds__(256, 2)
void caps_produce(const float* __restrict__ xf, const float* __restrict__ Wf,
                  unsigned short* __restrict__ u5, unsigned short* __restrict__ part)
{
    __shared__ __align__(16) char smem[57360];
    unsigned short* wl = (unsigned short*)smem;             // 2560 granules x 16B
    unsigned short* xl = (unsigned short*)(smem + 40960);   // 1024 granules x 16B
    unsigned short* zp = (unsigned short*)(smem + 57344);   // 16B zeros

    const int tid = threadIdx.x, lane = tid & 63, w = tid >> 6;
    const int bl = lane & 15, kg = lane >> 4;
    const int bg = blockIdx.x, ig = blockIdx.y;
    const int i0 = ig * 16, b0 = bg * 64;
    const int b  = b0 + w * 16 + bl;
    const int brow = w * 16 + bl;

    if (tid < 8) zp[tid] = 0;

    // stage W: granule g = il*160 + j*16 + d  <-  W[j, i0+il, d, 0:8]
#pragma unroll
    for (int r = 0; r < 10; ++r) {
        int g  = tid + r * 256;
        int il = g / 160, rem = g - il * 160;
        int j  = rem >> 4, d = rem & 15;
        const float4* s = (const float4*)(Wf + (((size_t)j * NI + i0 + il) * 16 + d) * 8);
        float4 a = s[0], c = s[1];
        u16x8 o;
        o[0]=f2bf(a.x); o[1]=f2bf(a.y); o[2]=f2bf(a.z); o[3]=f2bf(a.w);
        o[4]=f2bf(c.x); o[5]=f2bf(c.y); o[6]=f2bf(c.z); o[7]=f2bf(c.w);
        *(u16x8*)(wl + g * 8) = o;
    }
    // stage x: slot (br*16+sg) holds x[b0+br, i0 + (sg^(br&7)), 0:8]  (bank-safe)
#pragma unroll
    for (int r = 0; r < 4; ++r) {
        int g  = tid + r * 256;
        int br = g >> 4, sg = g & 15;
        int gr = sg ^ (br & 7);
        const float4* s = (const float4*)(xf + ((size_t)(b0 + br) * NI + i0 + gr) * 8);
        float4 a = s[0], c = s[1];
        u16x8 o;
        o[0]=f2bf(a.x); o[1]=f2bf(a.y); o[2]=f2bf(a.z); o[3]=f2bf(a.w);
        o[4]=f2bf(c.x); o[5]=f2bf(c.y); o[6]=f2bf(c.z); o[7]=f2bf(c.w);
        *(u16x8*)(xl + g * 8) = o;
    }
    __syncthreads();

    const f32x4 zero = {0.f, 0.f, 0.f, 0.f};
    f32x4 sacc[NJ];
#pragma unroll
    for (int j = 0; j < NJ; ++j) sacc[j] = zero;

#pragma unroll 2
    for (int it = 0; it < 16; ++it) {
        bf16x8 xv = *(const bf16x8*)(xl + (brow * 16 + (it ^ (brow & 7))) * 8);
        f32x4 uh[NJ];
#pragma unroll
        for (int j = 0; j < NJ; ++j) {
            const unsigned short* ap = (kg == 0)
                ? (wl + ((it * 10 + j) * 16 + bl) * 8) : zp;
            uh[j] = __builtin_amdgcn_mfma_f32_16x16x32_bf16(*(const bf16x8*)ap, xv, zero, 0, 0, 0);
        }
#pragma unroll
        for (int j = 0; j < NJ; ++j) sacc[j] += uh[j];

        // store u5 granule G = ((i*5+jp)*512 + b)*4 + kg  (wave => 1KB dense per jp)
        unsigned short* up = u5 + (((size_t)(i0 + it) * 5 * 512 + b) * 4 + kg) * 8;
#pragma unroll
        for (int jp = 0; jp < 5; ++jp) {
            f32x4 ua = uh[2 * jp], ub2 = uh[2 * jp + 1];
            u16x8 o;
            o[0]=f2bf(ua[0]); o[1]=f2bf(ua[1]); o[2]=f2bf(ua[2]); o[3]=f2bf(ua[3]);
            o[4]=f2bf(ub2[0]); o[5]=f2bf(ub2[1]); o[6]=f2bf(ub2[2]); o[7]=f2bf(ub2[3]);
            *(u16x8*)(up + (size_t)jp * 16384) = o;
        }
    }

    // epilogue: iter-0 partial -> LDS bounce -> dense bf16 store
    __syncthreads();
    float* s_out = (float*)smem;
#pragma unroll
    for (int j = 0; j < NJ; ++j)
        *(f32x4*)(s_out + brow * 164 + j * 16 + kg * 4) = sacc[j];
    __syncthreads();
    unsigned short* pp = part + ((size_t)ig * NB + b0) * 160;
#pragma unroll
    for (int r = 0; r < 10; ++r) {
        int idx = tid + r * 256;
        int br  = idx / 40, f4 = idx - br * 40;
        f32x4 v = *(const f32x4*)(s_out + br * 164 + f4 * 4);
        ushort4 o;
        o.x = f2bf(v[0]); o.y = f2bf(v[1]); o.z = f2bf(v[2]); o.w = f2bf(v[3]);
        *(ushort4*)(pp + idx * 4) = o;
    }
}

// Consumer: pure stream. Per i: 5 x 16B loads (1KB/instr dense) -> logits ->
// softmax -> sacc. No MFMA, no W, no staging. g kept packed; cvt on use.
__global__ __launch_bounds__(256, 2)
void caps_consume(const unsigned short* __restrict__ u5,
                  const float* __restrict__ vsum_g,
                  unsigned short* __restrict__ part)
{
    __shared__ __align__(16) float s_out[64 * 164];

    const int tid = threadIdx.x, lane = tid & 63, w = tid >> 6;
    const int bl = lane & 15, kg = lane >> 4;
    const int bg = blockIdx.x, ig = blockIdx.y;
    const int i0 = ig * 16, b0 = bg * 64;
    const int b  = b0 + w * 16 + bl;
    const int brow = w * 16 + bl;

    f32x4 vs[NJ];
#pragma unroll
    for (int j = 0; j < NJ; ++j)
        vs[j] = *(const f32x4*)(vsum_g + (size_t)b * 160 + j * 16 + kg * 4);

    f32x4 sacc[NJ];
#pragma unroll
    for (int j = 0; j < NJ; ++j) sacc[j] = {0.f, 0.f, 0.f, 0.f};

    const unsigned short* ub = u5 + (((size_t)i0 * 5 * 512 + b) * 4 + kg) * 8;

#pragma unroll 2
    for (int it = 0; it < 16; ++it) {
        const unsigned short* up = ub + (size_t)it * 81920;
        u16x8 g[5];
#pragma unroll
        for (int jp = 0; jp < 5; ++jp)
            g[jp] = *(const u16x8*)(up + (size_t)jp * 16384);

        float bd[NJ];
#pragma unroll
        for (int jp = 0; jp < 5; ++jp) {
            bd[2*jp]   = bf2f(g[jp][0])*vs[2*jp][0]   + bf2f(g[jp][1])*vs[2*jp][1]
                       + bf2f(g[jp][2])*vs[2*jp][2]   + bf2f(g[jp][3])*vs[2*jp][3];
            bd[2*jp+1] = bf2f(g[jp][4])*vs[2*jp+1][0] + bf2f(g[jp][5])*vs[2*jp+1][1]
                       + bf2f(g[jp][6])*vs[2*jp+1][2] + bf2f(g[jp][7])*vs[2*jp+1][3];
        }
#pragma unroll
        for (int j = 0; j < NJ; ++j) {
            bd[j] += __shfl_xor(bd[j], 16, 64);   // reduce the 4 d-quads
            bd[j] += __shfl_xor(bd[j], 32, 64);
        }
        float m = bd[0];
#pragma unroll
        for (int j = 1; j < NJ; ++j) m = fmaxf(m, bd[j]);
        float Z = 0.f;
#pragma unroll
        for (int j = 0; j < NJ; ++j) { bd[j] = __expf(bd[j] - m); Z += bd[j]; }
        const float rZ = 1.f / Z;
#pragma unroll
        for (int jp = 0; jp < 5; ++jp) {
            const float c0 = bd[2*jp] * rZ, c1 = bd[2*jp+1] * rZ;
#pragma unroll
            for (int dd = 0; dd < 4; ++dd) {
                sacc[2*jp][dd]   += c0 * bf2f(g[jp][dd]);
                sacc[2*jp+1][dd] += c1 * bf2f(g[jp][4 + dd]);
            }
        }
    }

    __syncthreads();
#pragma unroll
    for (int j = 0; j < NJ; ++j)
        *(f32x4*)(s_out + brow * 164 + j * 16 + kg * 4) = sacc[j];
    __syncthreads();
    unsigned short* pp = part + ((size_t)ig * NB + b0) * 160;
#pragma unroll
    for (int r = 0; r < 10; ++r) {
        int idx = tid + r * 256;
        int br  = idx / 40, f4 = idx - br * 40;
        f32x4 v = *(const f32x4*)(s_out + br * 164 + f4 * 4);
        ushort4 o;
        o.x = f2bf(v[0]); o.y = f2bf(v[1]); o.z = f2bf(v[2]); o.w = f2bf(v[3]);
        *(ushort4*)(pp + idx * 4) = o;
    }
}

// Sum nsl bf16 partials, scale, squash over d (16-lane shfl), update vsum/out.
__global__ __launch_bounds__(256)
void squash_reduce(const unsigned short* __restrict__ part, int nsl,
                   float* __restrict__ vsum_g, float* __restrict__ out,
                   float alpha, int mode)
{
    const int t = blockIdx.x * 256 + threadIdx.x;   // < 81920 = b*160 + j*16 + d
    const unsigned short* p = part + t;
    float a0 = 0.f, a1 = 0.f, a2 = 0.f, a3 = 0.f;
    for (int ig = 0; ig < nsl; ig += 4) {
        a0 += bf2f(p[(size_t)ig * 81920]);
        a1 += bf2f(p[(size_t)(ig + 1) * 81920]);
        a2 += bf2f(p[(size_t)(ig + 2) * 81920]);
        a3 += bf2f(p[(size_t)(ig + 3) * 81920]);
    }
    const float s = ((a0 + a1) + (a2 + a3)) * alpha;

    float sq = s * s;
    sq += __shfl_xor(sq, 1, 64);
    sq += __shfl_xor(sq, 2, 64);
    sq += __shfl_xor(sq, 4, 64);
    sq += __shfl_xor(sq, 8, 64);
    const float sc = sq / ((1.f + sq) * sqrtf(sq + EPS_));
    const float v  = sc * s;

    if (mode == 0)      vsum_g[t] = v;
    else if (mode == 1) vsum_g[t] += v;
    else                out[t] = v;
}

// ============================ FALLBACK (R6, proven 286us) ============================

constexpr size_t XB_ELEMS = (size_t)NB * NI * 8;
constexpr size_t WB_ELEMS = (size_t)NJ * NI * ND * 8;
constexpr int    XQ = 1179648, WQ = 368640;

__global__ __launch_bounds__(256)
void conv_bf16(const float* __restrict__ x, const float* __restrict__ Wg,
               unsigned short* __restrict__ xb, unsigned short* __restrict__ wb)
{
    int t = blockIdx.x * 256 + threadIdx.x;
    if (t < XQ) {
        float4 v = ((const float4*)x)[t];
        ushort4 o; o.x=f2bf(v.x); o.y=f2bf(v.y); o.z=f2bf(v.z); o.w=f2bf(v.w);
        ((ushort4*)xb)[t] = o;
    } else if (t - XQ < WQ) {
        int u = t - XQ;
        float4 v = ((const float4*)Wg)[u];
        ushort4 o; o.x=f2bf(v.x); o.y=f2bf(v.y); o.z=f2bf(v.z); o.w=f2bf(v.w);
        ((ushort4*)wb)[u] = o;
    } else if (t - XQ - WQ < 2) {
        ushort4 z; z.x=z.y=z.z=z.w=0;
        ((ushort4*)wb)[WQ + (t - XQ - WQ)] = z;
    }
}

template <int MODE>
__global__ __launch_bounds__(256, 2)
void caps_fb(const unsigned short* __restrict__ xb, const unsigned short* __restrict__ wb,
             const unsigned short* __restrict__ zpad, const float* __restrict__ vsum_g,
             unsigned short* __restrict__ part)
{
    __shared__ float s_red[16 * 160];
    const int tid = threadIdx.x, lane = tid & 63, w = tid >> 6;
    const int bl = lane & 15, kg = lane >> 4;
    const int bg = blockIdx.x, ig = blockIdx.y;
    const int b = bg * 16 + bl;
    const int i0 = ig * 72 + w * 18;

    for (int k = tid; k < 2560; k += 256) s_red[k] = 0.f;
    const f32x4 zero = {0.f, 0.f, 0.f, 0.f};
    f32x4 sacc[NJ];
#pragma unroll
    for (int j = 0; j < NJ; ++j) sacc[j] = zero;

    if (MODE == 0) {
        const unsigned short* xpt = xb + ((size_t)b * NI + i0 + kg) * 8;
        const unsigned short* wpt = wb + ((size_t)(i0 + kg)) * 128 + bl * 8;
#pragma unroll
        for (int t = 0; t < 4; ++t) {
            bf16x8 af[NJ];
#pragma unroll
            for (int j = 0; j < NJ; ++j)
                af[j] = *(const bf16x8*)(wpt + (size_t)j * NI * 128 + t * 512);
            bf16x8 bf = *(const bf16x8*)(xpt + t * 32);
#pragma unroll
            for (int j = 0; j < NJ; ++j)
                sacc[j] = __builtin_amdgcn_mfma_f32_16x16x32_bf16(af[j], bf, sacc[j], 0, 0, 0);
        }
        {
            const unsigned short* wt = (kg < 2) ? (wb + (size_t)(i0 + 16 + kg) * 128 + bl * 8) : zpad;
            const size_t jstr = (kg < 2) ? (size_t)NI * 128 : 0;
            bf16x8 af[NJ];
#pragma unroll
            for (int j = 0; j < NJ; ++j) af[j] = *(const bf16x8*)(wt + j * jstr);
            bf16x8 bf = *(const bf16x8*)(xb + ((size_t)b * NI + i0 + 16 + (kg & 1)) * 8);
#pragma unroll
            for (int j = 0; j < NJ; ++j)
                sacc[j] = __builtin_amdgcn_mfma_f32_16x16x32_bf16(af[j], bf, sacc[j], 0, 0, 0);
        }
    } else {
        f32x4 vs[NJ];
#pragma unroll
        for (int j = 0; j < NJ; ++j)
            vs[j] = *(const f32x4*)(vsum_g + (size_t)b * 160 + j * 16 + kg * 4);
        const unsigned short* xrow = xb + ((size_t)b * NI + i0) * 8;
        const unsigned short* wrow = (kg == 0) ? (wb + (size_t)i0 * 128 + bl * 8) : zpad;
        const size_t jstr = (kg == 0) ? (size_t)NI * 128 : 0;
        const size_t istp = (kg == 0) ? 128 : 0;
#pragma unroll 2
        for (int t = 0; t < 18; ++t) {
            bf16x8 af[NJ];
            const unsigned short* wr = wrow + (size_t)t * istp;
#pragma unroll
            for (int j = 0; j < NJ; ++j) af[j] = *(const bf16x8*)(wr + j * jstr);
            bf16x8 xv = *(const bf16x8*)(xrow + t * 8);
            f32x4 uh[NJ];
#pragma unroll
            for (int j = 0; j < NJ; ++j)
                uh[j] = __builtin_amdgcn_mfma_f32_16x16x32_bf16(af[j], xv, zero, 0, 0, 0);
            float bd[NJ];
#pragma unroll
            for (int j = 0; j < NJ; ++j) {
                float v = uh[j][0]*vs[j][0] + uh[j][1]*vs[j][1] + uh[j][2]*vs[j][2] + uh[j][3]*vs[j][3];
                v += __shfl_xor(v, 16, 64);
                v += __shfl_xor(v, 32, 64);
                bd[j] = v;
            }
            float m = bd[0];
#pragma unroll
            for (int j = 1; j < NJ; ++j) m = fmaxf(m, bd[j]);
            float Z = 0.f;
#pragma unroll
            for (int j = 0; j < NJ; ++j) { bd[j] = __expf(bd[j] - m); Z += bd[j]; }
            const float rZ = 1.f / Z;
#pragma unroll
            for (int j = 0; j < NJ; ++j) { const float c = bd[j] * rZ; sacc[j] += c * uh[j]; }
        }
    }

    __syncthreads();
    const int base = bl * 160 + kg * 4;
#pragma unroll
    for (int j = 0; j < NJ; ++j)
#pragma unroll
        for (int r = 0; r < 4; ++r)
            atomicAdd(&s_red[base + j * 16 + r], sacc[j][r]);
    __syncthreads();
    unsigned short* pp = part + ((size_t)ig * NB + bg * 16) * 160;
    for (int k = tid; k < 2560; k += 256) pp[k] = f2bf(s_red[k]);
}

// ============================ launch ============================

extern "C" void kernel_launch(void* const* d_in, const int* in_sizes, int n_in,
                              void* d_out, int out_size, void* d_ws, size_t ws_size,
                              hipStream_t stream)
{
    const float* inp = (const float*)d_in[0];
    const float* Wg  = (const float*)d_in[1];
    float* out = (float*)d_out;

    if (ws_size >= WS_MAIN) {
        unsigned short* u5   = (unsigned short*)d_ws;
        unsigned short* part = u5 + U5_SH;
        float* vsum = (float*)(part + PART_SH);

        dim3 grid(8, 72);
        caps_produce<<<grid, 256, 0, stream>>>(inp, Wg, u5, part);
        squash_reduce<<<320, 256, 0, stream>>>(part, 72, vsum, out, 0.1f, 0);
        caps_consume<<<grid, 256, 0, stream>>>(u5, vsum, part);
        squash_reduce<<<320, 256, 0, stream>>>(part, 72, vsum, out, 1.0f, 1);
        caps_consume<<<grid, 256, 0, stream>>>(u5, vsum, part);
        squash_reduce<<<320, 256, 0, stream>>>(part, 72, vsum, out, 1.0f, 2);
    } else {
        unsigned short* xbp  = (unsigned short*)d_ws;
        unsigned short* wbp  = xbp + XB_ELEMS;
        unsigned short* zp   = wbp + WB_ELEMS;
        unsigned short* part = zp + 16;
        float* vsum = (float*)(part + (size_t)16 * NB * 160);

        conv_bf16<<<(XQ + WQ + 2 + 255) / 256, 256, 0, stream>>>(inp, Wg, xbp, wbp);
        dim3 grid(32, 16);
        caps_fb<0><<<grid, 256, 0, stream>>>(xbp, wbp, zp, nullptr, part);
        squash_reduce<<<320, 256, 0, stream>>>(part, 16, vsum, out, 0.1f, 0);
        caps_fb<1><<<grid, 256, 0, stream>>>(xbp, wbp, zp, vsum, part);
        squash_reduce<<<320, 256, 0, stream>>>(part, 16, vsum, out, 1.0f, 1);
        caps_fb<1><<<grid, 256, 0, stream>>>(xbp, wbp, zp, vsum, part);
        squash_reduce<<<320, 256, 0, stream>>>(part, 16, vsum, out, 1.0f, 2);
    }
}

// Round 12
// 185.800 us; speedup vs baseline: 3.2988x; 1.0901x over previous
//
#include <hip/hip_runtime.h>

// DigiCaps dynamic routing — recompute strategy with clean LDS staging.
// inputs [512,1152,8] f32, W [10,1152,16,8] f32, out v [512,10,16] f32.
// u_hat[b,j,i,d] = sum_k x[b,i,k] W[j,i,d,k]; logits b_t = u_hat . vsum
// (vsum = running sum of v's) -> u_hat never materialized.
//
// R11 forensics: ordinary-load + ds_write staging runs CLEAN (producer hit
// 4.9 TB/s purposeful traffic; the R8-R10 ~0.5GB/pass phantom FETCH+WRITE is
// isolated to the global_load_lds path). R12 = R11's producer structure with
// the 188MB u5 store deleted: stage bf16 W-tile (40KB) + swizzled x-tile
// (16KB) per block via ordinary loads, MFMA from LDS, routing in registers,
// LDS-bounce bf16 partials epilogue. Block = 64 b x 16 i, grid (8,72).
// MFMA f32_16x16x32_bf16, C-layout: lane&15=b(col), (lane>>4)*4+reg=d(row);
// A: kg==0 lanes carry W k=0..7, kg>0 read a zeroed granule -> exact K=8.
// Verified R4-R11, absmax ~4e-3 (threshold 17.5e-3).

#define NB 512
#define NI 1152
#define NJ 10
#define ND 16

typedef short          bf16x8 __attribute__((ext_vector_type(8)));
typedef unsigned short u16x8  __attribute__((ext_vector_type(8)));
typedef float          f32x4  __attribute__((ext_vector_type(4)));

constexpr float EPS_ = 1e-7f;

constexpr size_t XB_ELEMS = (size_t)NB * NI * 8;       // bf16
constexpr size_t WB_ELEMS = (size_t)NJ * NI * ND * 8;  // bf16
constexpr int    XQ = 1179648;                         // x float4 quads
constexpr int    WQ = 368640;                          // W float4 quads
constexpr int    NIGB = 72;                            // i-groups of 16

__device__ inline unsigned short f2bf(float f) {   // RNE f32->bf16
    unsigned u = __float_as_uint(f);
    return (unsigned short)((u + 0x7fffu + ((u >> 16) & 1u)) >> 16);
}
__device__ inline float bf2f(unsigned short u) {
    return __uint_as_float((unsigned)u << 16);
}

__global__ __launch_bounds__(256)
void conv_bf16(const float* __restrict__ x, const float* __restrict__ Wg,
               unsigned short* __restrict__ xb, unsigned short* __restrict__ wb)
{
    int t = blockIdx.x * 256 + threadIdx.x;
    if (t < XQ) {
        float4 v = ((const float4*)x)[t];
        ushort4 o; o.x=f2bf(v.x); o.y=f2bf(v.y); o.z=f2bf(v.z); o.w=f2bf(v.w);
        ((ushort4*)xb)[t] = o;
    } else if (t - XQ < WQ) {
        int u = t - XQ;
        float4 v = ((const float4*)Wg)[u];
        ushort4 o; o.x=f2bf(v.x); o.y=f2bf(v.y); o.z=f2bf(v.z); o.w=f2bf(v.w);
        ((ushort4*)wb)[u] = o;
    }
}

// Block: 64 b (4 waves x 16) x 16 i. Full tile staged upfront (single
// stage, one barrier), K-loop fully LDS-fed.
template <int MODE>
__global__ __launch_bounds__(256, 2)
void caps_pass(const unsigned short* __restrict__ xb,
               const unsigned short* __restrict__ wb,
               const float* __restrict__ vsum_g,
               unsigned short* __restrict__ part)
{
    // smem map (bytes): [0,40960) wl 2560 granules [il][j][d];
    // [40960,57344) xl 1024 granules (XOR-swizzled); [57344,57360) zp.
    // Epilogue re-uses [0,41984) as float s_out[64][164].
    __shared__ __align__(16) char smem[57360];
    unsigned short* wl = (unsigned short*)smem;
    unsigned short* xl = (unsigned short*)(smem + 40960);
    unsigned short* zp = (unsigned short*)(smem + 57344);

    const int tid = threadIdx.x, lane = tid & 63, w = tid >> 6;
    const int bl = lane & 15, kg = lane >> 4;
    const int bg = blockIdx.x, ig = blockIdx.y;
    const int i0 = ig * 16, b0 = bg * 64;
    const int b  = b0 + w * 16 + bl;
    const int brow = w * 16 + bl;

    if (tid < 8) zp[tid] = 0;

    // stage W: granule g = il*160 + j*16 + d <- wb[j, i0+il, d, 0:8]
    // consecutive tid -> consecutive d -> contiguous 16B chunks (coalesced).
#pragma unroll
    for (int r = 0; r < 10; ++r) {
        int g  = tid + r * 256;
        int il = g / 160, rem = g - il * 160;
        const unsigned short* src =
            wb + ((size_t)(rem >> 4) * NI + (i0 + il)) * 128 + (rem & 15) * 8;
        *(u16x8*)(wl + g * 8) = *(const u16x8*)src;
    }
    // stage x: slot (br*16+sg) holds x[b0+br, i0 + (sg^(br&7)), 0:8]
#pragma unroll
    for (int r = 0; r < 4; ++r) {
        int g  = tid + r * 256;
        int br = g >> 4, sg = g & 15;
        int gr = sg ^ (br & 7);
        *(u16x8*)(xl + g * 8) =
            *(const u16x8*)(xb + ((size_t)(b0 + br) * NI + i0 + gr) * 8);
    }

    f32x4 vs[NJ];
    if (MODE == 1) {
#pragma unroll
        for (int j = 0; j < NJ; ++j)
            vs[j] = *(const f32x4*)(vsum_g + (size_t)b * 160 + j * 16 + kg * 4);
    }

    __syncthreads();

    const f32x4 zero = {0.f, 0.f, 0.f, 0.f};
    f32x4 sacc[NJ];
#pragma unroll
    for (int j = 0; j < NJ; ++j) sacc[j] = zero;

#pragma unroll 2
    for (int it = 0; it < 16; ++it) {
        bf16x8 xv = *(const bf16x8*)(xl + (brow * 16 + (it ^ (brow & 7))) * 8);

        f32x4 uh[NJ];
#pragma unroll
        for (int j = 0; j < NJ; ++j) {
            const unsigned short* ap = (kg == 0)
                ? (wl + ((it * 10 + j) * 16 + bl) * 8) : zp;
            bf16x8 af = *(const bf16x8*)ap;
            if (MODE == 0)
                sacc[j] = __builtin_amdgcn_mfma_f32_16x16x32_bf16(af, xv, sacc[j], 0, 0, 0);
            else
                uh[j] = __builtin_amdgcn_mfma_f32_16x16x32_bf16(af, xv, zero, 0, 0, 0);
        }

        if (MODE == 1) {
            float bd[NJ];
#pragma unroll
            for (int j = 0; j < NJ; ++j) {
                float v = uh[j][0] * vs[j][0] + uh[j][1] * vs[j][1]
                        + uh[j][2] * vs[j][2] + uh[j][3] * vs[j][3];
                v += __shfl_xor(v, 16, 64);   // reduce the 4 d-quads
                v += __shfl_xor(v, 32, 64);
                bd[j] = v;
            }
            float m = bd[0];
#pragma unroll
            for (int j = 1; j < NJ; ++j) m = fmaxf(m, bd[j]);
            float Z = 0.f;
#pragma unroll
            for (int j = 0; j < NJ; ++j) { bd[j] = __expf(bd[j] - m); Z += bd[j]; }
            const float rZ = 1.f / Z;
#pragma unroll
            for (int j = 0; j < NJ; ++j) {
                const float c = bd[j] * rZ;
                sacc[j] += c * uh[j];
            }
        }
    }

    // epilogue: sacc -> LDS bounce -> dense contiguous bf16 partials
    __syncthreads();
    float* s_out = (float*)smem;
#pragma unroll
    for (int j = 0; j < NJ; ++j)
        *(f32x4*)(s_out + brow * 164 + j * 16 + kg * 4) = sacc[j];
    __syncthreads();
    unsigned short* pp = part + ((size_t)ig * NB + b0) * 160;
#pragma unroll
    for (int r = 0; r < 10; ++r) {
        int idx = tid + r * 256;                 // 2560 float4 chunks = 64x160
        int br  = idx / 40, f4 = idx - br * 40;
        f32x4 v = *(const f32x4*)(s_out + br * 164 + f4 * 4);
        ushort4 o;
        o.x = f2bf(v[0]); o.y = f2bf(v[1]); o.z = f2bf(v[2]); o.w = f2bf(v[3]);
        *(ushort4*)(pp + idx * 4) = o;           // 512B contiguous per wave
    }
}

// Sum 72 bf16 ig-partials, scale, squash over d (16-lane shfl), update vsum/out.
__global__ __launch_bounds__(256)
void squash_reduce(const unsigned short* __restrict__ part,
                   float* __restrict__ vsum_g, float* __restrict__ out,
                   float alpha, int mode)
{
    const int t = blockIdx.x * 256 + threadIdx.x;   // < 81920 = b*160 + j*16 + d
    const unsigned short* p = part + t;
    float a0 = 0.f, a1 = 0.f, a2 = 0.f, a3 = 0.f;
#pragma unroll
    for (int ig = 0; ig < NIGB; ig += 4) {
        a0 += bf2f(p[(size_t)ig * 81920]);
        a1 += bf2f(p[(size_t)(ig + 1) * 81920]);
        a2 += bf2f(p[(size_t)(ig + 2) * 81920]);
        a3 += bf2f(p[(size_t)(ig + 3) * 81920]);
    }
    const float s = ((a0 + a1) + (a2 + a3)) * alpha;

    float sq = s * s;
    sq += __shfl_xor(sq, 1, 64);
    sq += __shfl_xor(sq, 2, 64);
    sq += __shfl_xor(sq, 4, 64);
    sq += __shfl_xor(sq, 8, 64);
    const float sc = sq / ((1.f + sq) * sqrtf(sq + EPS_));
    const float v  = sc * s;

    if (mode == 0)      vsum_g[t] = v;
    else if (mode == 1) vsum_g[t] += v;
    else                out[t] = v;
}

extern "C" void kernel_launch(void* const* d_in, const int* in_sizes, int n_in,
                              void* d_out, int out_size, void* d_ws, size_t ws_size,
                              hipStream_t stream)
{
    const float* inp = (const float*)d_in[0];
    const float* Wg  = (const float*)d_in[1];
    float* out = (float*)d_out;

    unsigned short* xbp  = (unsigned short*)d_ws;
    unsigned short* wbp  = xbp + XB_ELEMS;
    unsigned short* part = wbp + WB_ELEMS;                    // [72][512][160] bf16
    float* vsum = (float*)(part + (size_t)NIGB * NB * 160);   // [512][10][16] f32

    conv_bf16<<<(XQ + WQ + 255) / 256, 256, 0, stream>>>(inp, Wg, xbp, wbp);

    dim3 grid(8, NIGB);   // (8,72) = 576 blocks
    // iter 0: c uniform 1/10 (folded into alpha)
    caps_pass<0><<<grid, 256, 0, stream>>>(xbp, wbp, nullptr, part);
    squash_reduce<<<320, 256, 0, stream>>>(part, vsum, out, 0.1f, 0);
    // iter 1: logits = u_hat . v0
    caps_pass<1><<<grid, 256, 0, stream>>>(xbp, wbp, vsum, part);
    squash_reduce<<<320, 256, 0, stream>>>(part, vsum, out, 1.0f, 1);
    // iter 2: logits = u_hat . (v0+v1)
    caps_pass<1><<<grid, 256, 0, stream>>>(xbp, wbp, vsum, part);
    squash_reduce<<<320, 256, 0, stream>>>(part, vsum, out, 1.0f, 2);
}